// Round 12
// baseline (1984.352 us; speedup 1.0000x reference)
//
#include <hip/hip_runtime.h>
#include <math.h>

// ---------------------------------------------------------------------------
// RNN_63153199120819 — Round 12: atomic-RMW-return poll barrier.
// Hang pattern across R5-R11: every sc0-LOAD poll hangs (R9, R11); every
// atomic-load poll passes (R5/R8/R10). Model: sc0 loads can hit a stale L1
// line, and a polling wave generates no traffic to evict it (sibling waves
// parked at s_barrier) -> infinite spin. Data loads are safe only because
// each phase's 32KB A-traffic fully turns over L1 before any h reuse.
// Fix: poll = global_atomic_add(addr, 0) with sc0 (return old) — atomics
// bypass L1 and execute at the SAME coherence point as the arrival
// global_atomic_add (L2 if no-sc1 atomics are L2-executed, else LLC).
// Arrival/poll agree by construction -> cannot hang; speed reveals the point.
// Everything else identical to round 10 (passed, 1957us).
// ---------------------------------------------------------------------------

namespace {
constexpr int kT   = 128;
constexpr int kB   = 1024;
constexpr int kLag = 6;
constexpr int kH   = 256;
constexpr int kTc  = 32;          // MLP time chunk
constexpr int kMc  = kTc * kB;    // 32768 rows / chunk
constexpr int kGS  = 67;          // LDS gate row stride (f32)
constexpr int kLdsForce = 98304;  // >80KB => at most 1 block/CU
}

typedef _Float16 half8 __attribute__((ext_vector_type(8)));
typedef _Float16 half2 __attribute__((ext_vector_type(2)));
typedef float f32x4 __attribute__((ext_vector_type(4)));
typedef unsigned long long u64;

__device__ __forceinline__ float sigm(float x) {
    return 1.f / (1.f + exp2f(-1.4426950408889634f * x));
}
__device__ __forceinline__ float tanh_(float x) {
    return 2.f / (1.f + exp2f(-2.8853900817779268f * x)) - 1.f;
}

__device__ __forceinline__ half8 pack(u64 a, u64 b) {
    union { u64 u[2]; half8 h; } r;
    r.u[0] = a; r.u[1] = b;
    return r.h;
}

// ---- inline-asm memory ops ------------------------------------------------
// L1-bypass-intent load served by the XCD's shared L2 (data path: correctness
// additionally protected by full L1 turnover each phase — see header note).
__device__ __forceinline__ void ld_l2(half8& d, const _Float16* p) {
    asm volatile("global_load_dwordx4 %0, %1, off sc0"
                 : "=v"(d) : "v"(p) : "memory");
}
__device__ __forceinline__ void ld_pln(half8& d, const _Float16* p) {
    asm volatile("global_load_dwordx4 %0, %1, off"
                 : "=v"(d) : "v"(p) : "memory");
}
// fire-and-forget atomic increment (executes at the line's coherence point)
__device__ __forceinline__ void atomic_add_nr(unsigned int* p, unsigned int v) {
    asm volatile("global_atomic_add %0, %1, off"
                 :: "v"(p), "v"(v) : "memory");
}
// atomic add-0 with return: reads the authoritative value at the SAME
// coherence point where the arrival atomics execute; bypasses L1.
__device__ __forceinline__ unsigned int atomic_rd(unsigned int* p) {
    unsigned int d;
    unsigned int z = 0u;
    asm volatile("global_atomic_add %0, %1, %2, off sc0\n\ts_waitcnt vmcnt(0)"
                 : "=v"(d) : "v"(p), "v"(z) : "memory");
    return d;
}
// wait for all outstanding VMEM; ties the 16 loaded values into the dep chain
#define WAITCNT_HOLD16(A)                                                     \
    asm volatile("s_waitcnt vmcnt(0)"                                         \
        : "+v"(A[0]), "+v"(A[1]), "+v"(A[2]), "+v"(A[3]),                     \
          "+v"(A[4]), "+v"(A[5]), "+v"(A[6]), "+v"(A[7]),                     \
          "+v"(A[8]), "+v"(A[9]), "+v"(A[10]), "+v"(A[11]),                   \
          "+v"(A[12]), "+v"(A[13]), "+v"(A[14]), "+v"(A[15]))

// ---------------- prep kernels ---------------------------------------------
__global__ __launch_bounds__(256)
void zero_fill(unsigned int* __restrict__ p)
{
    p[blockIdx.x * 256 + threadIdx.x] = 0u;
}

__global__ __launch_bounds__(256)
void cvt_f2h(const float* __restrict__ s, _Float16* __restrict__ d)
{
    const int i = blockIdx.x * 256 + threadIdx.x;
    d[i] = (_Float16)s[i];
}

__global__ __launch_bounds__(256)
void build_wcat(const float* __restrict__ Wih, const float* __restrict__ Whh,
                _Float16* __restrict__ d)
{
    const int i = blockIdx.x * 256 + threadIdx.x;   // over 1024*512
    const int row = i >> 9, col = i & 511;
    const float v = (col < 256) ? Wih[row * 256 + col] : Whh[row * 256 + col - 256];
    d[i] = (_Float16)v;
}

__global__ __launch_bounds__(256)
void add_bias(const float* __restrict__ a, const float* __restrict__ b,
              float* __restrict__ d)
{
    const int i = blockIdx.x * 256 + threadIdx.x;
    d[i] = a[i] + b[i];
}

// ---------------- first layer: u1 = relu(x @ Wi1^T + bi1), K=6, fp16 out ---
__global__ __launch_bounds__(256)
void in_mlp1(const float* __restrict__ x, const float* __restrict__ Wi1,
             const float* __restrict__ bi1, _Float16* __restrict__ out)
{
    const int idx = blockIdx.x * 256 + threadIdx.x;   // over Mc*H
    const int col = idx & (kH - 1);
    const int row = idx >> 8;
    const float* xr = x + (size_t)row * kLag;
    const float* w  = Wi1 + col * kLag;
    float s = bi1[col];
#pragma unroll
    for (int k = 0; k < kLag; ++k) s = fmaf(xr[k], w[k], s);
    out[idx] = (_Float16)fmaxf(s, 0.f);
}

// ---------------- fp16 MFMA GEMM v2 (unchanged, validated) -----------------
__global__ __launch_bounds__(256)
void gemm_h16(const _Float16* __restrict__ A, const _Float16* __restrict__ W,
              const float* __restrict__ bias, _Float16* __restrict__ C)
{
    const int tid = threadIdx.x;
    const int w = tid >> 6, lane = tid & 63, q = lane >> 4, l15 = lane & 15;
    const int n0 = blockIdx.x * 64;
    const int r0 = blockIdx.y * 128 + w * 32;

    half8 bf[4][8];
#pragma unroll
    for (int nt = 0; nt < 4; ++nt)
#pragma unroll
        for (int kk = 0; kk < 8; ++kk)
            bf[nt][kk] = *(const half8*)(W + (size_t)(n0 + nt * 16 + l15) * 256
                                         + kk * 32 + q * 8);
    float bz[4];
#pragma unroll
    for (int nt = 0; nt < 4; ++nt) bz[nt] = bias[n0 + nt * 16 + l15];

#pragma unroll
    for (int rt = 0; rt < 2; ++rt) {
        const _Float16* arow = A + (size_t)(r0 + rt * 16 + l15) * 256 + q * 8;
        half8 af[8];
#pragma unroll
        for (int kk = 0; kk < 8; ++kk) af[kk] = *(const half8*)(arow + kk * 32);
        f32x4 acc[4];
#pragma unroll
        for (int nt = 0; nt < 4; ++nt)
            acc[nt] = (f32x4){bz[nt], bz[nt], bz[nt], bz[nt]};
#pragma unroll
        for (int kk = 0; kk < 8; ++kk)
#pragma unroll
            for (int nt = 0; nt < 4; ++nt)
                acc[nt] = __builtin_amdgcn_mfma_f32_16x16x32_f16(
                    af[kk], bf[nt][kk], acc[nt], 0, 0, 0);
#pragma unroll
        for (int nt = 0; nt < 4; ++nt)
#pragma unroll
            for (int r = 0; r < 4; ++r) {
                const float v = fmaxf(acc[nt][r], 0.f);
                C[(size_t)(r0 + rt * 16 + q * 4 + r) * 256 + n0 + nt * 16 + l15]
                    = (_Float16)v;
            }
    }
}

// ---------------- persistent LSTM helpers ----------------------------------
// barrier: drain data stores, arrive via atomic inc, poll via atomic add-0
// with return (same coherence point as the inc -> cannot miss the update).
__device__ __forceinline__ void xbar(unsigned int* __restrict__ cptr,
                                     unsigned int target, int tid)
{
    asm volatile("s_waitcnt vmcnt(0)" ::: "memory");   // data stores -> L2
    __syncthreads();
    if (tid == 0) {
        atomic_add_nr(cptr, 1u);
        while (atomic_rd(cptr) < target)
            __builtin_amdgcn_s_sleep(1);
    }
    __syncthreads();
}

// lo-only gather for prologue (plain compiler loads)
__device__ __forceinline__ void gather_lo(const _Float16* lo, int row, int q,
                                          u64* ua)
{
    const u64* plo = (const u64*)(lo + (size_t)row * 256 + q * 8);
#pragma unroll
    for (int kk = 0; kk < 8; ++kk) {
        ua[2*kk]   = plo[kk*8];
        ua[2*kk+1] = plo[kk*8 + 1];
    }
}

__device__ __forceinline__ void gstore(float* __restrict__ gl, int m0, int nb,
                                       int q, int l15,
                                       const f32x4& a0, const f32x4& a1)
{
#pragma unroll
    for (int r = 0; r < 4; ++r) {
        gl[(m0 + q*4 + r) * kGS + nb + l15]      = a0[r];
        gl[(m0 + q*4 + r) * kGS + nb + 16 + l15] = a1[r];
    }
}

// one gate GEMM: A = [lo || hi] (64x512), this wave's 2 col-tiles, 2 row-tiles
template<bool CLO>
__device__ __forceinline__ void phase_gemm(
    const _Float16* __restrict__ lo, const _Float16* __restrict__ hi,
    const half8 (&B0)[16], const half8 (&B1)[16],
    float* __restrict__ gl, int rtb, int nb, int q, int l15)
{
#pragma unroll
    for (int rt = 0; rt < 2; ++rt) {
        const int row = (rtb + rt) * 16 + l15;
        const _Float16* plo = lo + (size_t)row * 256 + q * 8;
        const _Float16* phi = hi + (size_t)row * 256 + q * 8;
        half8 A[16];
#pragma unroll
        for (int kk = 0; kk < 8; ++kk) {
            if (CLO) ld_l2(A[kk], plo + kk * 32);
            else     ld_pln(A[kk], plo + kk * 32);
            ld_l2(A[8 + kk], phi + kk * 32);
        }
        WAITCNT_HOLD16(A);
        f32x4 a0 = {0.f,0.f,0.f,0.f}, a1 = {0.f,0.f,0.f,0.f};
#pragma unroll
        for (int kk = 0; kk < 16; ++kk) {
            a0 = __builtin_amdgcn_mfma_f32_16x16x32_f16(A[kk], B0[kk], a0, 0,0,0);
            a1 = __builtin_amdgcn_mfma_f32_16x16x32_f16(A[kk], B1[kk], a1, 0,0,0);
        }
        gstore(gl, (rtb + rt) * 16, nb, q, l15, a0, a1);
    }
}

// cell: h + relu->u stored with PLAIN stores (land in the shared XCD L2)
__device__ __forceinline__ void cell_one(const float* __restrict__ gl,
    int crow, int cc, const float* __restrict__ bs, float* __restrict__ cst,
    _Float16* __restrict__ hout, _Float16* __restrict__ uout)
{
    const float* gr = gl + crow * kGS;
    _Float16 hp[2];
#pragma unroll
    for (int e = 0; e < 2; ++e) {
        const float gi = gr[0*16 + cc + e] + bs[e*4 + 0];
        const float gf = gr[1*16 + cc + e] + bs[e*4 + 1];
        const float gg = gr[2*16 + cc + e] + bs[e*4 + 2];
        const float go = gr[3*16 + cc + e] + bs[e*4 + 3];
        const float c2 = sigm(gf) * cst[e] + sigm(gi) * tanh_(gg);
        cst[e] = c2;
        hp[e] = (_Float16)(sigm(go) * tanh_(c2));
    }
    *(half2*)(hout + (size_t)crow * 256 + cc) = (half2){hp[0], hp[1]};
    if (uout) {
        const _Float16 z = (_Float16)0.f;
        *(half2*)(uout + (size_t)crow * 256 + cc) =
            (half2){hp[0] > z ? hp[0] : z, hp[1] > z ? hp[1] : z};
    }
}

// ---------------- persistent LSTM kernel -----------------------------------
__global__ __launch_bounds__(512, 2)
void lstm_all(_Float16* __restrict__ ubuf,
              const _Float16* __restrict__ Wc0, const _Float16* __restrict__ Wc1,
              const float* __restrict__ bc0, const float* __restrict__ bc1,
              _Float16* __restrict__ h0b, _Float16* __restrict__ h1b,
              unsigned int* __restrict__ cnt)
{
    extern __shared__ char lds[];
    float* gl0 = (float*)lds;             // [64][kGS] layer-0 gates
    float* gl1 = gl0 + 64 * kGS;          // [64][kGS] layer-1 gates

    const int tid = threadIdx.x;
    const int w = tid >> 6, lane = tid & 63, q = lane >> 4, l15 = lane & 15;
    const int wl = w & 3;
    const int rtb = (wl >> 1) * 2;        // row-tile base (0 or 2)
    const int nb  = (wl & 1) * 32;        // gate-col base (0 or 32)
    const int lyr = (w < 4) ? 1 : 0;      // wave's layer

    // ---- XCD discovery -> (bi, js): 96KB LDS => 1 block/CU => 32/XCD ----
    __shared__ int sh_bi, sh_js;
    if (tid == 0) {
        unsigned int xcd = __builtin_amdgcn_s_getreg(20 | (31 << 11)) & 7u;
        unsigned int rank = __hip_atomic_fetch_add(cnt + 512 + xcd * 16, 1u,
            __ATOMIC_RELAXED, __HIP_MEMORY_SCOPE_AGENT);
        sh_bi = (int)(xcd * 2 + (rank >> 4));
        sh_js = (int)(rank & 15);
    }
    __syncthreads();
    const int bi = sh_bi, js = sh_js;
    unsigned int* cptr = cnt + bi * 32;   // group counter line

    // ---- B-fragments of this wave's layer/cols -> 32 half8 in registers ----
    const _Float16* WcL = lyr ? Wc1 : Wc0;
    half8 Bf0[16], Bf1[16];
    {
        const _Float16* wr0 = WcL
            + (size_t)((nb >> 4) * 256 + js * 16 + l15) * 512 + q * 8;
        const _Float16* wr1 = WcL
            + (size_t)(((nb >> 4) + 1) * 256 + js * 16 + l15) * 512 + q * 8;
#pragma unroll
        for (int kk = 0; kk < 16; ++kk) {
            Bf0[kk] = *(const half8*)(wr0 + kk * 32);
            Bf1[kk] = *(const half8*)(wr1 + kk * 32);
        }
    }

    // ---- per-thread biases / states (cell: row tid>>3, cols cc, cc+1) ----
    const int cc = (tid & 7) * 2;
    const int crow = tid >> 3;
    float bs0[8], bs1[8];
#pragma unroll
    for (int e = 0; e < 2; ++e)
#pragma unroll
        for (int g = 0; g < 4; ++g) {
            bs0[e*4 + g] = bc0[g * 256 + js * 16 + cc + e];
            bs1[e*4 + g] = bc1[g * 256 + js * 16 + cc + e];
        }
    float cst0[2] = {0.f, 0.f}, cst1[2] = {0.f, 0.f};
    const size_t rbase = (size_t)bi * 64 * 256;
    const size_t obase = rbase + js * 16;

    // ---- prologue: h0(0) = cell([u(0) | 0] @ W0^T) -> h0b parity 0 ----
    if (lyr == 0) {
#pragma unroll
        for (int rt = 0; rt < 2; ++rt) {
            u64 ua[16];
            gather_lo(ubuf + rbase, (rtb + rt) * 16 + l15, q, ua);
            f32x4 a0 = {0.f,0.f,0.f,0.f}, a1 = {0.f,0.f,0.f,0.f};
#pragma unroll
            for (int kk = 0; kk < 8; ++kk) {
                const half8 af = pack(ua[2*kk], ua[2*kk+1]);
                a0 = __builtin_amdgcn_mfma_f32_16x16x32_f16(af, Bf0[kk], a0, 0,0,0);
                a1 = __builtin_amdgcn_mfma_f32_16x16x32_f16(af, Bf1[kk], a1, 0,0,0);
            }
            gstore(gl0, (rtb + rt) * 16, nb, q, l15, a0, a1);
        }
    }
    __syncthreads();
    cell_one(gl0, crow, cc, bs0, cst0, h0b + obase, nullptr);
    xbar(cptr, 16u, tid);

    // ---- fused phases: t computes h1(t) (waves 0-3) + h0(t+1) (waves 4-7) --
    for (int t = 0; t < kT; ++t) {
        const size_t p  = (size_t)(t & 1) * kB * 256;
        const size_t pn = (size_t)((t & 1) ^ 1) * kB * 256;
        const bool hasB = (t < kT - 1);
        if (lyr == 1) {
            // layer-1 A = [h0(t) | h1(t-1)]
            phase_gemm<true>(h0b + p + rbase, h1b + pn + rbase,
                             Bf0, Bf1, gl1, rtb, nb, q, l15);
        } else if (hasB) {
            // layer-0 A = [u(t+1) | h0(t)]
            phase_gemm<false>(ubuf + (size_t)(t + 1) * kB * 256 + rbase,
                              h0b + p + rbase,
                              Bf0, Bf1, gl0, rtb, nb, q, l15);
        }
        __syncthreads();
        cell_one(gl1, crow, cc, bs1, cst1, h1b + p + obase,
                 ubuf + (size_t)t * kB * 256 + obase);
        if (hasB) {
            cell_one(gl0, crow, cc, bs0, cst0, h0b + pn + obase, nullptr);
            xbar(cptr, (unsigned)(16 * (t + 2)), tid);
        }
    }
}

// ---------------- last layer: y = y2 @ Wo3^T + bo3, N=6, fp16 in -----------
__global__ __launch_bounds__(256)
void out_mlp3(const _Float16* __restrict__ y2, const float* __restrict__ Wo3,
              const float* __restrict__ bo3, float* __restrict__ out)
{
    const int lane = threadIdx.x & 63;
    const int row  = blockIdx.x * 4 + (threadIdx.x >> 6);
    const _Float16* yr = y2 + (size_t)row * kH + lane * 4;
    const float a0 = (float)yr[0], a1 = (float)yr[1], a2 = (float)yr[2], a3 = (float)yr[3];
    float s[kLag];
#pragma unroll
    for (int o = 0; o < kLag; ++o) {
        const float4 wv = *(const float4*)(Wo3 + o * kH + lane * 4);
        s[o] = a0 * wv.x + a1 * wv.y + a2 * wv.z + a3 * wv.w;
    }
#pragma unroll
    for (int off = 32; off > 0; off >>= 1) {
#pragma unroll
        for (int o = 0; o < kLag; ++o) s[o] += __shfl_down(s[o], off);
    }
    if (lane == 0) {
#pragma unroll
        for (int o = 0; o < kLag; ++o)
            out[(size_t)row * kLag + o] = s[o] + bo3[o];
    }
}

// ---------------------------------------------------------------------------
extern "C" void kernel_launch(void* const* d_in, const int* in_sizes, int n_in,
                              void* d_out, int out_size, void* d_ws, size_t ws_size,
                              hipStream_t stream)
{
    const float* x    = (const float*)d_in[0];
    const float* Wi1  = (const float*)d_in[1];
    const float* bi1  = (const float*)d_in[2];
    const float* Wi2  = (const float*)d_in[3];
    const float* bi2  = (const float*)d_in[4];
    const float* Wi3  = (const float*)d_in[5];
    const float* bi3  = (const float*)d_in[6];
    const float* Wih0 = (const float*)d_in[7];
    const float* Whh0 = (const float*)d_in[8];
    const float* bih0 = (const float*)d_in[9];
    const float* bhh0 = (const float*)d_in[10];
    const float* Wih1 = (const float*)d_in[11];
    const float* Whh1 = (const float*)d_in[12];
    const float* bih1 = (const float*)d_in[13];
    const float* bhh1 = (const float*)d_in[14];
    const float* Wo1  = (const float*)d_in[15];
    const float* bo1  = (const float*)d_in[16];
    const float* Wo2  = (const float*)d_in[17];
    const float* bo2  = (const float*)d_in[18];
    const float* Wo3  = (const float*)d_in[19];
    const float* bo3  = (const float*)d_in[20];
    float* outp = (float*)d_out;

    // ---- workspace layout (~106 MB) ----
    char* p = (char*)d_ws;
    _Float16* ubuf = (_Float16*)p;  p += (size_t)kT * kB * kH * 2;   // 67.1 MB
    _Float16* s1   = (_Float16*)p;  p += (size_t)kMc * kH * 2;       // 16.8 MB
    _Float16* s2   = (_Float16*)p;  p += (size_t)kMc * kH * 2;       // 16.8 MB
    _Float16* Wc0  = (_Float16*)p;  p += (size_t)1024 * 512 * 2;     // 1 MB
    _Float16* Wc1  = (_Float16*)p;  p += (size_t)1024 * 512 * 2;     // 1 MB
    _Float16* W2h  = (_Float16*)p;  p += (size_t)kH * kH * 2;
    _Float16* W3h  = (_Float16*)p;  p += (size_t)kH * kH * 2;
    _Float16* Wo1h = (_Float16*)p;  p += (size_t)kH * kH * 2;
    _Float16* Wo2h = (_Float16*)p;  p += (size_t)kH * kH * 2;
    float* bc0 = (float*)p;  p += 1024 * 4;
    float* bc1 = (float*)p;  p += 1024 * 4;
    // zeroed region: h double-buffers + counters (contiguous)
    _Float16* h0b = (_Float16*)p;  p += (size_t)2 * kB * kH * 2;     // 1 MB
    _Float16* h1b = (_Float16*)p;  p += (size_t)2 * kB * kH * 2;     // 1 MB
    unsigned int* cnt = (unsigned int*)p;  p += 4096;  // 16 group + 8 xcd ctrs

    // ---- prep ----
    zero_fill<<<2052, 256, 0, stream>>>((unsigned int*)h0b);
    cvt_f2h<<<kH * kH / 256, 256, 0, stream>>>(Wi2, W2h);
    cvt_f2h<<<kH * kH / 256, 256, 0, stream>>>(Wi3, W3h);
    cvt_f2h<<<kH * kH / 256, 256, 0, stream>>>(Wo1, Wo1h);
    cvt_f2h<<<kH * kH / 256, 256, 0, stream>>>(Wo2, Wo2h);
    build_wcat<<<1024 * 512 / 256, 256, 0, stream>>>(Wih0, Whh0, Wc0);
    build_wcat<<<1024 * 512 / 256, 256, 0, stream>>>(Wih1, Whh1, Wc1);
    add_bias<<<4, 256, 0, stream>>>(bih0, bhh0, bc0);
    add_bias<<<4, 256, 0, stream>>>(bih1, bhh1, bc1);

    // ---- input MLP (chunked): x -> s1 -> s2 -> ubuf ----
    for (int c = 0; c < kT / kTc; ++c) {
        in_mlp1<<<kMc * kH / 256, 256, 0, stream>>>(
            x + (size_t)c * kMc * kLag, Wi1, bi1, s1);
        gemm_h16<<<dim3(4, kMc / 128), 256, 0, stream>>>(s1, W2h, bi2, s2);
        gemm_h16<<<dim3(4, kMc / 128), 256, 0, stream>>>(
            s2, W3h, bi3, ubuf + (size_t)c * kMc * kH);
    }

    // ---- LSTM: cooperative, weights in VGPRs, atomic-RMW barrier ----
    static bool attr_set = false;
    if (!attr_set) {
        hipFuncSetAttribute((const void*)lstm_all,
                            hipFuncAttributeMaxDynamicSharedMemorySize, kLdsForce);
        attr_set = true;
    }
    void* args[] = {&ubuf, &Wc0, &Wc1, &bc0, &bc1, &h0b, &h1b, &cnt};
    hipLaunchCooperativeKernel((const void*)lstm_all, dim3(256), dim3(512),
                               args, kLdsForce, stream);

    // ---- output MLP (chunked): ubuf -> s1 -> s2 -> out ----
    for (int c = 0; c < kT / kTc; ++c) {
        gemm_h16<<<dim3(4, kMc / 128), 256, 0, stream>>>(
            ubuf + (size_t)c * kMc * kH, Wo1h, bo1, s1);
        gemm_h16<<<dim3(4, kMc / 128), 256, 0, stream>>>(s1, Wo2h, bo2, s2);
        out_mlp3<<<kMc / 4, 256, 0, stream>>>(
            s2, Wo3, bo3, outp + (size_t)c * kMc * kLag);
    }
}